// Round 3
// baseline (99.520 us; speedup 1.0000x reference)
//
#include <hip/hip_runtime.h>

// SetConv RBF: B=4, NQ=4096, NC=4096, DC=2, DY=8, fp32.
// out[b,q,0:8] = sum_c w(q,c)*y[c] / (den+1e-8); out[b,q,8] = den = sum_c w(q,c)
// w = exp(-|xq-xc|^2 / (2*ls^2)), ls = exp(log_length_scale)
//
// NOTE (measured R2): dur_us includes ~50 us of harness overhead (268 MB d_ws
// 0xAA poison fill at ~44 us shows up as fillBufferAligned). Only ~43 us was
// our kernels; optimize kernel time, ignore the fixed floor.

#define BB 4
#define NQ 4096
#define NC 4096
#define DY 8
#define NBQ (BB * NQ)           // 16384 queries total

#if __has_builtin(__builtin_amdgcn_exp2f)
#define EXP2F(x) __builtin_amdgcn_exp2f(x)
#else
#define EXP2F(x) exp2f(x)
#endif

// ---------------- fast path: LDS-staged, 4 queries/thread, SPLIT=64 ----------
#define SPLIT 64
#define CCH (NC / SPLIT)        // 64 contexts per block
#define QT 4                    // queries per thread
#define QPB (256 * QT)          // 1024 queries per block
#define JS ((size_t)SPLIT * NBQ)                       // 1,048,576
#define WS_FLOATS ((size_t)(DY + 1) * SPLIT * NBQ)     // 9.4M floats = 37.7 MB

__global__ __launch_bounds__(256, 4) void setconv_accum_ws(
    const float* __restrict__ xq, const float* __restrict__ xc,
    const float* __restrict__ yc, const float* __restrict__ lls,
    float* __restrict__ ws)
{
    __shared__ float4 sy[CCH * 2];   // yc tile: context c -> sy[2c], sy[2c+1]
    __shared__ float2 sx[CCH];       // xc tile

    const int bid   = blockIdx.x;            // 0..1023
    const int split = bid & (SPLIT - 1);
    const int qb    = bid >> 6;              // 0..15
    const int b     = qb >> 2;               // 1024 queries per block, 4096/batch
    const int q0    = qb * QPB;              // global flattened bq base
    const int tid   = threadIdx.x;
    const int c0    = split * CCH;

    // cooperative stage: 128 float4 of yc + 32 float4 of xc
    const float4* ysrc = (const float4*)(yc + ((size_t)b * NC + c0) * DY);
    const float4* xsrc = (const float4*)(xc + ((size_t)b * NC + c0) * 2);
    if (tid < CCH * 2) sy[tid] = ysrc[tid];
    else if (tid < CCH * 2 + CCH / 2) ((float4*)sx)[tid - CCH * 2] = xsrc[tid - CCH * 2];

    // w = exp(-d2/(2*ls^2)) = exp2(d2 * negk), negk = -log2(e)/2 * exp(-2L)
    const float L    = lls[0];
    const float negk = -0.72134752044448f * EXP2F(L * -2.8853900817779268f);

    float qx[QT], qy[QT];
#pragma unroll
    for (int i = 0; i < QT; ++i) {
        const float2 qv = ((const float2*)xq)[q0 + tid + 256 * i];  // coalesced
        qx[i] = qv.x; qy[i] = qv.y;
    }

    float acc[QT][DY], den[QT];
#pragma unroll
    for (int i = 0; i < QT; ++i) {
        den[i] = 0.f;
#pragma unroll
        for (int j = 0; j < DY; ++j) acc[i][j] = 0.f;
    }

    __syncthreads();

#pragma unroll 4
    for (int c = 0; c < CCH; ++c) {
        const float2 cv = sx[c];             // LDS broadcast, conflict-free
        const float4 y0 = sy[2 * c + 0];
        const float4 y1 = sy[2 * c + 1];
#pragma unroll
        for (int i = 0; i < QT; ++i) {
            const float dx = qx[i] - cv.x;
            const float dy = qy[i] - cv.y;
            const float d2 = fmaf(dy, dy, dx * dx);
            const float w  = EXP2F(d2 * negk);   // v_exp_f32
            den[i] += w;
            acc[i][0] = fmaf(w, y0.x, acc[i][0]);
            acc[i][1] = fmaf(w, y0.y, acc[i][1]);
            acc[i][2] = fmaf(w, y0.z, acc[i][2]);
            acc[i][3] = fmaf(w, y0.w, acc[i][3]);
            acc[i][4] = fmaf(w, y1.x, acc[i][4]);
            acc[i][5] = fmaf(w, y1.y, acc[i][5]);
            acc[i][6] = fmaf(w, y1.z, acc[i][6]);
            acc[i][7] = fmaf(w, y1.w, acc[i][7]);
        }
    }

    // ws[j][split][bq] — consecutive tid -> consecutive addresses (coalesced)
#pragma unroll
    for (int i = 0; i < QT; ++i) {
        float* w0 = ws + (size_t)split * NBQ + (q0 + tid + 256 * i);
#pragma unroll
        for (int j = 0; j < DY; ++j) w0[j * JS] = acc[i][j];
        w0[DY * JS] = den[i];
    }
}

// Reduce over SPLIT=64 + normalize. Block: 64 queries, 4 split-groups of 16.
__global__ __launch_bounds__(256) void setconv_reduce(
    const float* __restrict__ ws, float* __restrict__ out)
{
    __shared__ float part[4][64][DY + 1];
    const int tid  = threadIdx.x;
    const int qi   = tid & 63;
    const int sg   = tid >> 6;
    const int base = blockIdx.x * 64;
    const int bq   = base + qi;

#pragma unroll
    for (int j = 0; j < DY + 1; ++j) {
        float s = 0.f;
#pragma unroll
        for (int k = 0; k < SPLIT / 4; ++k) {
            const int split = sg * (SPLIT / 4) + k;
            s += ws[(size_t)j * JS + (size_t)split * NBQ + bq];  // coalesced
        }
        part[sg][qi][j] = s;
    }
    __syncthreads();

    for (int it = tid; it < 64 * (DY + 1); it += 256) {
        const int q2 = it / (DY + 1);
        const int j  = it - q2 * (DY + 1);
        const float den = part[0][q2][DY] + part[1][q2][DY] +
                          part[2][q2][DY] + part[3][q2][DY];
        float v;
        if (j == DY) {
            v = den;
        } else {
            const float s = part[0][q2][j] + part[1][q2][j] +
                            part[2][q2][j] + part[3][q2][j];
            v = s / (den + 1e-8f);
        }
        out[(size_t)base * (DY + 1) + it] = v;
    }
}

// ---------------- fallback path (round-1, known-good): atomics ----------------
#define FSPLIT 8
#define FCCH (NC / FSPLIT)

__global__ __launch_bounds__(256) void setconv_zero(float4* __restrict__ out) {
    out[blockIdx.x * 256 + threadIdx.x] = make_float4(0.f, 0.f, 0.f, 0.f);
}

__global__ __launch_bounds__(256) void setconv_accum_atomic(
    const float* __restrict__ xq, const float* __restrict__ xc,
    const float* __restrict__ yc, const float* __restrict__ lls,
    float* __restrict__ out)
{
    const int bid   = blockIdx.x;
    const int split = bid & (FSPLIT - 1);
    const int qblk  = (bid / FSPLIT) & (NQ / 256 - 1);
    const int b     = bid / (FSPLIT * (NQ / 256));
    const int q     = qblk * 256 + threadIdx.x;

    const float L    = lls[0];
    const float negk = -0.72134752044448f * EXP2F(L * -2.8853900817779268f);

    const float2 qv = ((const float2*)xq)[b * NQ + q];
    const float qx0 = qv.x, qy0 = qv.y;

    float acc[DY];
#pragma unroll
    for (int j = 0; j < DY; ++j) acc[j] = 0.f;
    float den = 0.f;

    const float2* __restrict__ xcp = ((const float2*)xc) + (size_t)b * NC;
    const float4* __restrict__ ycp = ((const float4*)yc) + (size_t)b * NC * 2;

    const int c0 = split * FCCH;
#pragma unroll 4
    for (int c = c0; c < c0 + FCCH; ++c) {
        const float2 cv = xcp[c];
        const float4 y0 = ycp[2 * c + 0];
        const float4 y1 = ycp[2 * c + 1];
        const float dx = qx0 - cv.x;
        const float dy = qy0 - cv.y;
        const float d2 = fmaf(dy, dy, dx * dx);
        const float w  = EXP2F(d2 * negk);
        den += w;
        acc[0] = fmaf(w, y0.x, acc[0]);
        acc[1] = fmaf(w, y0.y, acc[1]);
        acc[2] = fmaf(w, y0.z, acc[2]);
        acc[3] = fmaf(w, y0.w, acc[3]);
        acc[4] = fmaf(w, y1.x, acc[4]);
        acc[5] = fmaf(w, y1.y, acc[5]);
        acc[6] = fmaf(w, y1.z, acc[6]);
        acc[7] = fmaf(w, y1.w, acc[7]);
    }

    float* o = out + (size_t)(b * NQ + q) * (DY + 1);
#pragma unroll
    for (int j = 0; j < DY; ++j) atomicAdd(o + j, acc[j]);
    atomicAdd(o + DY, den);
}

__global__ __launch_bounds__(256) void setconv_norm(float* __restrict__ out) {
    const int q = blockIdx.x * 256 + threadIdx.x;
    float* o = out + (size_t)q * (DY + 1);
    const float inv = 1.0f / (o[DY] + 1e-8f);
#pragma unroll
    for (int j = 0; j < DY; ++j) o[j] *= inv;
}

extern "C" void kernel_launch(void* const* d_in, const int* in_sizes, int n_in,
                              void* d_out, int out_size, void* d_ws, size_t ws_size,
                              hipStream_t stream) {
    const float* xq  = (const float*)d_in[0];  // (4,4096,2)
    const float* xc  = (const float*)d_in[1];  // (4,4096,2)
    const float* yc  = (const float*)d_in[2];  // (4,4096,8)
    const float* lls = (const float*)d_in[3];  // scalar
    float* out = (float*)d_out;                // (4,4096,9)

    if (ws_size >= WS_FLOATS * sizeof(float)) {
        float* ws = (float*)d_ws;
        setconv_accum_ws<<<(NBQ / QPB) * SPLIT, 256, 0, stream>>>(xq, xc, yc, lls, ws);
        setconv_reduce<<<NBQ / 64, 256, 0, stream>>>(ws, out);
    } else {
        setconv_zero<<<(NBQ * (DY + 1)) / 1024, 256, 0, stream>>>((float4*)out);
        setconv_accum_atomic<<<BB * (NQ / 256) * FSPLIT, 256, 0, stream>>>(xq, xc, yc, lls, out);
        setconv_norm<<<NBQ / 256, 256, 0, stream>>>(out);
    }
}

// Round 4
// 88.858 us; speedup vs baseline: 1.1200x; 1.1200x over previous
//
#include <hip/hip_runtime.h>

// SetConv RBF: B=4, NQ=4096, NC=4096, DC=2, DY=8, fp32.
// out[b,q,0:8] = sum_c w(q,c)*y[c] / (den+1e-8); out[b,q,8] = den = sum_c w(q,c)
// w = exp(-|xq-xc|^2 / (2*ls^2)), ls = exp(log_length_scale)
//
// MEASURED (R2/R3): dur_us includes ~47 us of harness d_ws poison fill
// (268 MB fillBufferAligned) that we cannot control. Controllable kernel
// time was ~49 us (R2, SPLIT=32 ws) / ~52 us (R3, SPLIT=64 ws: partials
// traffic 37.7 MB each way ate the accum gain). R4: in-block context
// split -> global split of only 8 -> ws 4.7 MB; VALU issue floor ~14.5 us.

#define BB 4
#define NQ 4096
#define NC 4096
#define DY 8
#define NBQ (BB * NQ)           // 16384 queries total

#if __has_builtin(__builtin_amdgcn_exp2f)
#define EXP2F(x) __builtin_amdgcn_exp2f(x)
#else
#define EXP2F(x) exp2f(x)
#endif

// ---------------- fast path ----------------
#define GSPLIT 8                     // global context split
#define QPB 64                       // queries per block (1 per lane)
#define CSPL 4                       // in-block context split (1 per wave)
#define CTILE (NC / GSPLIT)          // 512 contexts staged per block (20 KB)
#define CPT (CTILE / CSPL)           // 128 contexts per thread
#define JS ((size_t)GSPLIT * NBQ)                     // 131072
#define WS_FLOATS ((size_t)(DY + 1) * GSPLIT * NBQ)   // 1.18M floats = 4.7 MB

// grid = (NBQ/QPB) * GSPLIT = 256*8 = 2048 blocks; 8 blocks/CU (LDS-capped),
// 32 waves/CU. Inner loop is pure VALU + wave-uniform LDS broadcast.
__global__ __launch_bounds__(256, 8) void setconv_accum_ws(
    const float* __restrict__ xq, const float* __restrict__ xc,
    const float* __restrict__ yc, const float* __restrict__ lls,
    float* __restrict__ ws)
{
    __shared__ float4 smem[CTILE * 2 + CTILE / 2];   // 20 KB: sy tile + sx tile
    float4* sy  = smem;                 // [CTILE*2]  yc tile
    float4* sx4 = smem + CTILE * 2;     // [CTILE/2]  xc tile

    const int bid = blockIdx.x;          // 0..2047
    const int gs  = bid & (GSPLIT - 1);
    const int qb  = bid >> 3;            // 0..255
    const int b   = qb >> 6;             // 64 q-blocks per batch
    const int tid = threadIdx.x;
    const int qi  = tid & 63;
    const int si  = tid >> 6;            // wave index 0..3
    const int bq  = qb * QPB + qi;

    // cooperative stage: 1024 float4 of yc + 256 float4 of xc
    const float4* ysrc = (const float4*)(yc + ((size_t)b * NC + gs * CTILE) * DY);
    const float4* xsrc = (const float4*)(xc + ((size_t)b * NC + gs * CTILE) * 2);
#pragma unroll
    for (int i = 0; i < 4; ++i) sy[tid + 256 * i] = ysrc[tid + 256 * i];
    sx4[tid] = xsrc[tid];

    // w = exp(-d2/(2*ls^2)) = exp2(d2 * negk), negk = -log2(e)/2 * exp(-2L)
    const float L    = lls[0];
    const float negk = -0.72134752044448f * EXP2F(L * -2.8853900817779268f);

    const float2 qv = ((const float2*)xq)[bq];
    const float qx = qv.x, qy = qv.y;

    float acc[DY], den = 0.f;
#pragma unroll
    for (int j = 0; j < DY; ++j) acc[j] = 0.f;

    __syncthreads();

    const float2* sx = (const float2*)sx4;
    const int cbeg = si * CPT;
#pragma unroll 4
    for (int c = cbeg; c < cbeg + CPT; ++c) {
        const float2 cv = sx[c];         // wave-uniform -> LDS broadcast
        const float4 y0 = sy[2 * c + 0];
        const float4 y1 = sy[2 * c + 1];
        const float dx = qx - cv.x;
        const float dy = qy - cv.y;
        const float d2 = fmaf(dy, dy, dx * dx);
        const float w  = EXP2F(d2 * negk);   // v_exp_f32
        den += w;
        acc[0] = fmaf(w, y0.x, acc[0]);
        acc[1] = fmaf(w, y0.y, acc[1]);
        acc[2] = fmaf(w, y0.z, acc[2]);
        acc[3] = fmaf(w, y0.w, acc[3]);
        acc[4] = fmaf(w, y1.x, acc[4]);
        acc[5] = fmaf(w, y1.y, acc[5]);
        acc[6] = fmaf(w, y1.z, acc[6]);
        acc[7] = fmaf(w, y1.w, acc[7]);
    }

    // in-block 4->1 reduction; overlay partials on the tile buffer.
    __syncthreads();
    float* part = (float*)smem;          // [CSPL][QPB][9] = 9216 B, stride 9
    float* p = part + (size_t)(si * QPB + qi) * (DY + 1);
#pragma unroll
    for (int j = 0; j < DY; ++j) p[j] = acc[j];
    p[DY] = den;
    __syncthreads();

    if (tid < QPB) {                     // 64 lanes -> coalesced ws stores
        float* w0 = ws + (size_t)gs * NBQ + (qb * QPB + tid);
#pragma unroll
        for (int j = 0; j < DY + 1; ++j) {
            float s = 0.f;
#pragma unroll
            for (int k = 0; k < CSPL; ++k)
                s += part[(size_t)(k * QPB + tid) * (DY + 1) + j];
            w0[(size_t)j * JS] = s;
        }
    }
}

// Reduce over GSPLIT=8 + normalize. Block: 64 queries, 4 groups of 2 splits.
__global__ __launch_bounds__(256) void setconv_reduce(
    const float* __restrict__ ws, float* __restrict__ out)
{
    __shared__ float part[4][64][DY + 1];
    const int tid  = threadIdx.x;
    const int qi   = tid & 63;
    const int sg   = tid >> 6;
    const int base = blockIdx.x * 64;
    const int bq   = base + qi;

#pragma unroll
    for (int j = 0; j < DY + 1; ++j) {
        float s = 0.f;
#pragma unroll
        for (int k = 0; k < GSPLIT / 4; ++k) {
            const int split = sg * (GSPLIT / 4) + k;
            s += ws[(size_t)j * JS + (size_t)split * NBQ + bq];  // coalesced
        }
        part[sg][qi][j] = s;
    }
    __syncthreads();

    for (int it = tid; it < 64 * (DY + 1); it += 256) {
        const int q2 = it / (DY + 1);
        const int j  = it - q2 * (DY + 1);
        const float den = part[0][q2][DY] + part[1][q2][DY] +
                          part[2][q2][DY] + part[3][q2][DY];
        float v;
        if (j == DY) {
            v = den;
        } else {
            const float s = part[0][q2][j] + part[1][q2][j] +
                            part[2][q2][j] + part[3][q2][j];
            v = s / (den + 1e-8f);
        }
        out[(size_t)base * (DY + 1) + it] = v;    // coalesced
    }
}

// ---------------- fallback path (round-1, known-good): atomics ----------------
#define FSPLIT 8
#define FCCH (NC / FSPLIT)

__global__ __launch_bounds__(256) void setconv_zero(float4* __restrict__ out) {
    out[blockIdx.x * 256 + threadIdx.x] = make_float4(0.f, 0.f, 0.f, 0.f);
}

__global__ __launch_bounds__(256) void setconv_accum_atomic(
    const float* __restrict__ xq, const float* __restrict__ xc,
    const float* __restrict__ yc, const float* __restrict__ lls,
    float* __restrict__ out)
{
    const int bid   = blockIdx.x;
    const int split = bid & (FSPLIT - 1);
    const int qblk  = (bid / FSPLIT) & (NQ / 256 - 1);
    const int b     = bid / (FSPLIT * (NQ / 256));
    const int q     = qblk * 256 + threadIdx.x;

    const float L    = lls[0];
    const float negk = -0.72134752044448f * EXP2F(L * -2.8853900817779268f);

    const float2 qv = ((const float2*)xq)[b * NQ + q];
    const float qx0 = qv.x, qy0 = qv.y;

    float acc[DY], den = 0.f;
#pragma unroll
    for (int j = 0; j < DY; ++j) acc[j] = 0.f;

    const float2* __restrict__ xcp = ((const float2*)xc) + (size_t)b * NC;
    const float4* __restrict__ ycp = ((const float4*)yc) + (size_t)b * NC * 2;

    const int c0 = split * FCCH;
#pragma unroll 4
    for (int c = c0; c < c0 + FCCH; ++c) {
        const float2 cv = xcp[c];
        const float4 y0 = ycp[2 * c + 0];
        const float4 y1 = ycp[2 * c + 1];
        const float dx = qx0 - cv.x;
        const float dy = qy0 - cv.y;
        const float d2 = fmaf(dy, dy, dx * dx);
        const float w  = EXP2F(d2 * negk);
        den += w;
        acc[0] = fmaf(w, y0.x, acc[0]);
        acc[1] = fmaf(w, y0.y, acc[1]);
        acc[2] = fmaf(w, y0.z, acc[2]);
        acc[3] = fmaf(w, y0.w, acc[3]);
        acc[4] = fmaf(w, y1.x, acc[4]);
        acc[5] = fmaf(w, y1.y, acc[5]);
        acc[6] = fmaf(w, y1.z, acc[6]);
        acc[7] = fmaf(w, y1.w, acc[7]);
    }

    float* o = out + (size_t)(b * NQ + q) * (DY + 1);
#pragma unroll
    for (int j = 0; j < DY; ++j) atomicAdd(o + j, acc[j]);
    atomicAdd(o + DY, den);
}

__global__ __launch_bounds__(256) void setconv_norm(float* __restrict__ out) {
    const int q = blockIdx.x * 256 + threadIdx.x;
    float* o = out + (size_t)q * (DY + 1);
    const float inv = 1.0f / (o[DY] + 1e-8f);
#pragma unroll
    for (int j = 0; j < DY; ++j) o[j] *= inv;
}

extern "C" void kernel_launch(void* const* d_in, const int* in_sizes, int n_in,
                              void* d_out, int out_size, void* d_ws, size_t ws_size,
                              hipStream_t stream) {
    const float* xq  = (const float*)d_in[0];  // (4,4096,2)
    const float* xc  = (const float*)d_in[1];  // (4,4096,2)
    const float* yc  = (const float*)d_in[2];  // (4,4096,8)
    const float* lls = (const float*)d_in[3];  // scalar
    float* out = (float*)d_out;                // (4,4096,9)

    if (ws_size >= WS_FLOATS * sizeof(float)) {
        float* ws = (float*)d_ws;
        setconv_accum_ws<<<(NBQ / QPB) * GSPLIT, 256, 0, stream>>>(xq, xc, yc, lls, ws);
        setconv_reduce<<<NBQ / 64, 256, 0, stream>>>(ws, out);
    } else {
        setconv_zero<<<(NBQ * (DY + 1)) / 1024, 256, 0, stream>>>((float4*)out);
        setconv_accum_atomic<<<BB * (NQ / 256) * FSPLIT, 256, 0, stream>>>(xq, xc, yc, lls, out);
        setconv_norm<<<NBQ / 256, 256, 0, stream>>>(out);
    }
}